// Round 9
// baseline (713.069 us; speedup 1.0000x reference)
//
#include <hip/hip_runtime.h>
#include <hip/hip_bf16.h>

// RCNN: bidirectional simple-RNN + conv1x1 (fused) + global max pool + dense
// B=256 T=512 V=50000 E=128 H=256 C=128
//
// Round-9 structure: EW vocab table + EXACT full-length recurrence.
//  - EW[V][640] bf16 = [Wf^T e + bf | Wb^T e + bb | Wc_mid^T e]: computed
//    once per VOCAB row (50k) instead of per token (131k, 2.6x redundant).
//    rnn gathers its xw C-seed from EW[idx[b,t]]; pool gathers the e_cur
//    conv partial from cols [512,640). No xw buffer, no h stores.
//  - rnn: R4 config (32 blocks = 16 btiles x 2 dirs, 8 waves x 32 cols,
//    2 waves/SIMD, C-seeded MFMA, T-unroll x2, 2-pair gather pipeline,
//    LDS-only barrier), full T=512 — no truncation. Fused conv: p =
//    Wc_slice^T h (8 extra MFMA/wave) stored to pbuf (67.1 MB, CORRECTLY
//    sized this time — R8 under-allocated by 2x and clobbered weights).
//  - pool: p_f + p_c(gathered) + p_b -> max_t -> +bc, tanh -> atomicMax.

#define B_ 256
#define T_ 512
#define E_ 128
#define H_ 256
#define C_ 128
#define V_ 50000

typedef __attribute__((ext_vector_type(8))) short short8;
typedef __attribute__((ext_vector_type(4))) float float4v;
typedef __attribute__((ext_vector_type(2))) unsigned int uint2v;

__device__ inline unsigned short f2bf(float f) {
  unsigned u = __float_as_uint(f);
  u += 0x7fffu + ((u >> 16) & 1u);  // RNE
  return (unsigned short)(u >> 16);
}
__device__ inline unsigned pkbf(float a, float b) {
  __hip_bfloat162 h2 = __float22bfloat162_rn(float2{a, b});
  union { __hip_bfloat162 h; unsigned u; } cv;
  cv.h = h2;
  return cv.u;
}
__device__ inline float lo16f(unsigned u) { return __uint_as_float(u << 16); }
__device__ inline float hi16f(unsigned u) { return __uint_as_float(u & 0xffff0000u); }
__device__ inline float fast_tanh(float x) {
  float e = __expf(2.f * x);                 // inf ok -> 1
  float r = __builtin_amdgcn_rcpf(e + 1.f);
  return __builtin_fmaf(-2.f, r, 1.f);
}
__device__ inline unsigned enc_f(float f) {
  unsigned u = __float_as_uint(f);
  return (u & 0x80000000u) ? ~u : (u | 0x80000000u);
}
__device__ inline float dec_f(unsigned key) {
  unsigned bits = (key & 0x80000000u) ? (key ^ 0x80000000u) : ~key;
  return __uint_as_float(bits);
}
__device__ inline void sync_lds() {
  asm volatile("s_waitcnt lgkmcnt(0)\n\ts_barrier" ::: "memory");
}
__device__ inline int clampt(int t) { return t < 0 ? 0 : (t > 511 ? 511 : t); }

// ---------------------------------------------------------------------------
// prep: WT_all[640][128] = [Wf^T ; Wb^T ; Wc_mid^T] (A-layout for ew GEMM),
// biasEW[640] = [bf ; bb ; 0], WcT[128][640], UfT/UbT[256][256]. Coalesced
// reads, strided writes.
// ---------------------------------------------------------------------------
__global__ __launch_bounds__(256) void prep_kernel(
    const float* __restrict__ Wf, const float* __restrict__ Wb,
    const float* __restrict__ Wc, const float* __restrict__ Uf,
    const float* __restrict__ Ub, const float* __restrict__ bf_,
    const float* __restrict__ bb_,
    unsigned short* __restrict__ WT_all, float* __restrict__ biasEW,
    unsigned short* __restrict__ WcT, unsigned short* __restrict__ UfT,
    unsigned short* __restrict__ UbT) {
  int gid = blockIdx.x * 256 + threadIdx.x;
  int stride = gridDim.x * 256;
  for (int i = gid; i < 128 * 256; i += stride) {  // Wf/Wb [128][256]
    int k = i >> 8, m = i & 255;
    WT_all[m * 128 + k] = f2bf(Wf[i]);
    WT_all[(256 + m) * 128 + k] = f2bf(Wb[i]);
  }
  for (int i = gid; i < 640 * 128; i += stride) {  // Wc [640][128]
    int d = i >> 7, c = i & 127;
    unsigned short v = f2bf(Wc[i]);
    WcT[c * 640 + d] = v;
    if (d >= 256 && d < 384) WT_all[(512 + c) * 128 + (d - 256)] = v;
  }
  for (int i = gid; i < 256 * 256; i += stride) {  // Uf/Ub [256][256]
    int k = i >> 8, n = i & 255;
    UfT[n * 256 + k] = f2bf(Uf[i]);
    UbT[n * 256 + k] = f2bf(Ub[i]);
  }
  for (int i = gid; i < 640; i += stride)
    biasEW[i] = i < 256 ? bf_[i] : (i < 512 ? bb_[i - 256] : 0.f);
}

// ---------------------------------------------------------------------------
// ew: EW[V][640] = emb @ [Wf|Wb|Wc_mid] + biasEW, bf16. grid 3125 x 256 thr;
// block = 16 emb rows x 640 cols, 4 waves x 160 cols (10 m-tiles).
// ---------------------------------------------------------------------------
__global__ __launch_bounds__(256) void ew_kernel(
    const float* __restrict__ emb, const unsigned short* __restrict__ WT_all,
    const float* __restrict__ biasEW, unsigned short* __restrict__ EW) {
  const int r0 = blockIdx.x * 16;
  const int tid = threadIdx.x;
  const int w = tid >> 6, lane = tid & 63, q = lane >> 4, l15 = lane & 15;

  short8 wfr[10][4];
#pragma unroll
  for (int mt = 0; mt < 10; ++mt)
#pragma unroll
    for (int kt = 0; kt < 4; ++kt)
      wfr[mt][kt] = *(const short8*)(WT_all + (160 * w + 16 * mt + l15) * 128 +
                                     kt * 32 + q * 8);
  short8 efr[4];
#pragma unroll
  for (int kt = 0; kt < 4; ++kt) {
    const float* p8 = emb + (size_t)(r0 + l15) * E_ + kt * 32 + q * 8;
    float4v a0 = *(const float4v*)p8;
    float4v a1 = *(const float4v*)(p8 + 4);
    union { unsigned u[4]; short8 s; } cv;
    cv.u[0] = pkbf(a0[0], a0[1]);
    cv.u[1] = pkbf(a0[2], a0[3]);
    cv.u[2] = pkbf(a1[0], a1[1]);
    cv.u[3] = pkbf(a1[2], a1[3]);
    efr[kt] = cv.s;
  }
  float4v acc[10];
#pragma unroll
  for (int mt = 0; mt < 10; ++mt) acc[mt] = (float4v){0.f, 0.f, 0.f, 0.f};
#pragma unroll
  for (int kt = 0; kt < 4; ++kt)
#pragma unroll
    for (int mt = 0; mt < 10; ++mt)
      acc[mt] = __builtin_amdgcn_mfma_f32_16x16x32_bf16(wfr[mt][kt], efr[kt],
                                                        acc[mt], 0, 0, 0);
#pragma unroll
  for (int mt = 0; mt < 10; ++mt) {
    const int col = 160 * w + 16 * mt + 4 * q;
    float4v bv = *(const float4v*)(biasEW + col);
    float4v v = acc[mt] + bv;
    uint2v pk = {pkbf(v[0], v[1]), pkbf(v[2], v[3])};
    *(uint2v*)(EW + (size_t)(r0 + l15) * 640 + col) = pk;
  }
}

// ---------------------------------------------------------------------------
// rnn: EXACT full-length. blk = dir*16 + btile. 8 waves x 32 cols.
// h_t = tanh(U^T h ; C-seed = EW-gathered xw_t); each step also emits
// p(t_prev) = Wc_slice^T h(t_prev) from the already-loaded LDS fragment.
// ---------------------------------------------------------------------------
__global__ __launch_bounds__(512, 2) void rnn_kernel(
    const int* __restrict__ idxL, const int* __restrict__ idxR,
    const unsigned short* __restrict__ EW,
    const unsigned short* __restrict__ UfT,
    const unsigned short* __restrict__ UbT,
    const unsigned short* __restrict__ WcT, unsigned short* __restrict__ pbuf) {
  const int blk = blockIdx.x;
  const int btile = blk & 15;
  const int dir = blk >> 4;
  const int b0 = btile * 16;
  const int* __restrict__ idx = dir ? idxR : idxL;
  const unsigned short* __restrict__ UT = dir ? UbT : UfT;
  const int ewoff = dir ? 256 : 0;   // col offset in EW row
  const int wcoff = dir ? 384 : 0;   // k offset in WcT row
  const int tstep = dir ? -1 : 1;
  const int tstart = dir ? (T_ - 1) : 0;

  const int tid = threadIdx.x;
  const int wv = tid >> 6, lane = tid & 63, q = lane >> 4, l15 = lane & 15;

  __shared__ __attribute__((aligned(16))) unsigned short hbuf[2][16][280];
  unsigned short* hb0 = &hbuf[0][0][0];
  unsigned short* hb1 = &hbuf[1][0][0];
  for (int i = tid; i < 16 * 280; i += 512) hb0[i] = 0;

  // U^T A-fragments (32 out-cols/wave)
  short8 ufr[2][8];
#pragma unroll
  for (int mt = 0; mt < 2; ++mt)
#pragma unroll
    for (int kt = 0; kt < 8; ++kt)
      ufr[mt][kt] = *(const short8*)(UT + (32 * wv + 16 * mt + l15) * H_ +
                                     kt * 32 + q * 8);
  // Wc_slice^T A-fragments (16 p-cols/wave)
  short8 wcfr[8];
#pragma unroll
  for (int kt = 0; kt < 8; ++kt)
    wcfr[kt] = *(const short8*)(WcT + (size_t)(16 * wv + l15) * 640 + wcoff +
                                kt * 32 + q * 8);

  const int idxbase = (b0 + l15) * T_;
  const int eofs = ewoff + 32 * wv + 4 * q;

  // prologue: idx pair0+pair1; gather pair0
  int i0A = idx[idxbase + tstart];
  int i0B = idx[idxbase + tstart + tstep];
  int ihA = idx[idxbase + tstart + 2 * tstep];
  int ihB = idx[idxbase + tstart + 3 * tstep];
  uint2v curA[2], curB[2];
#pragma unroll
  for (int mt = 0; mt < 2; ++mt) {
    curA[mt] = *(const uint2v*)(EW + (size_t)i0A * 640 + eofs + 16 * mt);
    curB[mt] = *(const uint2v*)(EW + (size_t)i0B * 640 + eofs + 16 * mt);
  }

  // p store base (row = dir*128 + btile*8 + wv; lane 8B at 64q+4*l15)
  unsigned short* pwbase =
      pbuf + ((size_t)(dir * 128 + btile * 8 + wv) * T_) * 256 + 64 * q +
      4 * l15;

  const unsigned lrd = l15 * 280;
  const unsigned lwr = l15 * 280 + 32 * wv;

  __syncthreads();

  int tA = tstart;  // t of step A of current pair
#pragma unroll 1
  for (int p = 0; p < 256; ++p) {
    // idx loads for pair p+2
    int ilA = idx[idxbase + clampt(tA + 4 * tstep)];
    int ilB = idx[idxbase + clampt(tA + 5 * tstep)];
    // EW gathers for pair p+1
    uint2v nxtA[2], nxtB[2];
#pragma unroll
    for (int mt = 0; mt < 2; ++mt) {
      nxtA[mt] = *(const uint2v*)(EW + (size_t)ihA * 640 + eofs + 16 * mt);
      nxtB[mt] = *(const uint2v*)(EW + (size_t)ihB * 640 + eofs + 16 * mt);
    }

    // ---- STEP A (s=2p): read hb0 (h of step 2p-1), write hb1 ----
    {
      short8 afr[8];
#pragma unroll
      for (int kt = 0; kt < 8; ++kt)
        afr[kt] = *(const short8*)(hb0 + lrd + kt * 32 + q * 8);
      if (p >= 1) {  // p of h(step 2p-1), slot tA - tstep
        float4v pacc = (float4v){0.f, 0.f, 0.f, 0.f};
#pragma unroll
        for (int kt = 0; kt < 8; ++kt)
          pacc = __builtin_amdgcn_mfma_f32_16x16x32_bf16(wcfr[kt], afr[kt],
                                                         pacc, 0, 0, 0);
        uint2v pk = {pkbf(pacc[0], pacc[1]), pkbf(pacc[2], pacc[3])};
        *(uint2v*)(pwbase + (tA - tstep) * 256) = pk;
      }
      float4v acc[2];
#pragma unroll
      for (int mt = 0; mt < 2; ++mt)
        acc[mt] = (float4v){lo16f(curA[mt].x), hi16f(curA[mt].x),
                            lo16f(curA[mt].y), hi16f(curA[mt].y)};
#pragma unroll
      for (int kt = 0; kt < 8; ++kt)
#pragma unroll
        for (int mt = 0; mt < 2; ++mt)
          acc[mt] = __builtin_amdgcn_mfma_f32_16x16x32_bf16(
              ufr[mt][kt], afr[kt], acc[mt], 0, 0, 0);
#pragma unroll
      for (int mt = 0; mt < 2; ++mt) {
        uint2v hv = {pkbf(fast_tanh(acc[mt][0]), fast_tanh(acc[mt][1])),
                     pkbf(fast_tanh(acc[mt][2]), fast_tanh(acc[mt][3]))};
        *(uint2v*)(hb1 + lwr + 16 * mt + 4 * q) = hv;
      }
    }
    sync_lds();

    // ---- STEP B (s=2p+1): read hb1 (h of step 2p), write hb0 ----
    {
      short8 afr[8];
#pragma unroll
      for (int kt = 0; kt < 8; ++kt)
        afr[kt] = *(const short8*)(hb1 + lrd + kt * 32 + q * 8);
      {  // p of h(step 2p), slot tA
        float4v pacc = (float4v){0.f, 0.f, 0.f, 0.f};
#pragma unroll
        for (int kt = 0; kt < 8; ++kt)
          pacc = __builtin_amdgcn_mfma_f32_16x16x32_bf16(wcfr[kt], afr[kt],
                                                         pacc, 0, 0, 0);
        uint2v pk = {pkbf(pacc[0], pacc[1]), pkbf(pacc[2], pacc[3])};
        *(uint2v*)(pwbase + tA * 256) = pk;
      }
      float4v acc[2];
#pragma unroll
      for (int mt = 0; mt < 2; ++mt)
        acc[mt] = (float4v){lo16f(curB[mt].x), hi16f(curB[mt].x),
                            lo16f(curB[mt].y), hi16f(curB[mt].y)};
#pragma unroll
      for (int kt = 0; kt < 8; ++kt)
#pragma unroll
        for (int mt = 0; mt < 2; ++mt)
          acc[mt] = __builtin_amdgcn_mfma_f32_16x16x32_bf16(
              ufr[mt][kt], afr[kt], acc[mt], 0, 0, 0);
#pragma unroll
      for (int mt = 0; mt < 2; ++mt) {
        uint2v hv = {pkbf(fast_tanh(acc[mt][0]), fast_tanh(acc[mt][1])),
                     pkbf(fast_tanh(acc[mt][2]), fast_tanh(acc[mt][3]))};
        *(uint2v*)(hb0 + lwr + 16 * mt + 4 * q) = hv;
      }
    }
#pragma unroll
    for (int mt = 0; mt < 2; ++mt) {
      curA[mt] = nxtA[mt];
      curB[mt] = nxtB[mt];
    }
    ihA = ilA;
    ihB = ilB;
    tA += 2 * tstep;
    sync_lds();
  }

  // tail: p for the last h (step 511, in hb0), slot tA - tstep
  {
    short8 afr[8];
#pragma unroll
    for (int kt = 0; kt < 8; ++kt)
      afr[kt] = *(const short8*)(hb0 + lrd + kt * 32 + q * 8);
    float4v pacc = (float4v){0.f, 0.f, 0.f, 0.f};
#pragma unroll
    for (int kt = 0; kt < 8; ++kt)
      pacc = __builtin_amdgcn_mfma_f32_16x16x32_bf16(wcfr[kt], afr[kt], pacc,
                                                     0, 0, 0);
    uint2v pk = {pkbf(pacc[0], pacc[1]), pkbf(pacc[2], pacc[3])};
    *(uint2v*)(pwbase + (tA - tstep) * 256) = pk;
  }
}

// ---------------------------------------------------------------------------
// pool: pooled = tanh(max_t (p_f + p_c + p_b) + bc), p_c gathered from EW
// cols [512,640). grid 256 (16 btiles x 16 tchunks of 32 t), 256 thr.
// ---------------------------------------------------------------------------
__global__ __launch_bounds__(256) void pool_kernel(
    const int* __restrict__ idxC, const unsigned short* __restrict__ EW,
    const unsigned short* __restrict__ pbuf, const float* __restrict__ bc,
    unsigned int* __restrict__ pooled) {
  const int btile = blockIdx.x & 15;
  const int tch = blockIdx.x >> 4;
  const int b0 = btile * 16;
  const int tid = threadIdx.x;
  const int w = tid >> 6, lane = tid & 63, q = lane >> 4, l15 = lane & 15;
  const int loff = 64 * q + 4 * l15;

  float4v mx[8];
#pragma unroll
  for (int u = 0; u < 8; ++u)
    mx[u] = (float4v){-1e30f, -1e30f, -1e30f, -1e30f};

#pragma unroll 2
  for (int j = 0; j < 8; ++j) {
    const int t = tch * 32 + w * 8 + j;
    const int row = idxC[(b0 + l15) * T_ + t];
    const unsigned short* ecp = EW + (size_t)row * 640 + 512 + 4 * q;
#pragma unroll
    for (int u = 0; u < 8; ++u) {
      uint2v pf = *(const uint2v*)(pbuf +
                                   ((size_t)(btile * 8 + u) * T_ + t) * 256 +
                                   loff);
      uint2v pb = *(const uint2v*)(pbuf +
                                   ((size_t)(128 + btile * 8 + u) * T_ + t) *
                                       256 +
                                   loff);
      uint2v ec = *(const uint2v*)(ecp + 16 * u);
      float v0 = lo16f(pf.x) + lo16f(pb.x) + lo16f(ec.x);
      float v1 = hi16f(pf.x) + hi16f(pb.x) + hi16f(ec.x);
      float v2 = lo16f(pf.y) + lo16f(pb.y) + lo16f(ec.y);
      float v3 = hi16f(pf.y) + hi16f(pb.y) + hi16f(ec.y);
      mx[u][0] = fmaxf(mx[u][0], v0);
      mx[u][1] = fmaxf(mx[u][1], v1);
      mx[u][2] = fmaxf(mx[u][2], v2);
      mx[u][3] = fmaxf(mx[u][3], v3);
    }
  }
#pragma unroll
  for (int u = 0; u < 8; ++u) {
    float4v bcv = *(const float4v*)(bc + 16 * u + 4 * q);
#pragma unroll
    for (int i = 0; i < 4; ++i)
      atomicMax(pooled + (b0 + l15) * C_ + 16 * u + 4 * q + i,
                enc_f(fast_tanh(mx[u][i] + bcv[i])));
  }
}

// ---------------------------------------------------------------------------
// dense: out = sigmoid(pooled @ Wd + bd)  [256,128]@[128,2]
// ---------------------------------------------------------------------------
__global__ __launch_bounds__(256) void dense_kernel(
    const unsigned int* __restrict__ pooled, const float* __restrict__ Wd,
    const float* __restrict__ bd, float* __restrict__ out) {
  int b = threadIdx.x;
  float s0 = bd[0], s1 = bd[1];
#pragma unroll 4
  for (int c = 0; c < C_; ++c) {
    float f = dec_f(pooled[b * C_ + c]);
    s0 += f * Wd[c * 2 + 0];
    s1 += f * Wd[c * 2 + 1];
  }
  out[b * 2 + 0] = 1.f / (1.f + __expf(-s0));
  out[b * 2 + 1] = 1.f / (1.f + __expf(-s1));
}

// ---------------------------------------------------------------------------
extern "C" void kernel_launch(void* const* d_in, const int* in_sizes, int n_in,
                              void* d_out, int out_size, void* d_ws, size_t ws_size,
                              hipStream_t stream) {
  const int* idxC = (const int*)d_in[0];
  const int* idxL = (const int*)d_in[1];
  const int* idxR = (const int*)d_in[2];
  const float* emb = (const float*)d_in[3];
  const float* Wf = (const float*)d_in[4];
  const float* Uf = (const float*)d_in[5];
  const float* bf_ = (const float*)d_in[6];
  const float* Wb = (const float*)d_in[7];
  const float* Ub = (const float*)d_in[8];
  const float* bb_ = (const float*)d_in[9];
  const float* Wc = (const float*)d_in[10];
  const float* bc = (const float*)d_in[11];
  const float* Wd = (const float*)d_in[12];
  const float* bd = (const float*)d_in[13];

  char* ws = (char*)d_ws;
  unsigned short* EW = (unsigned short*)ws;                     //  64,000,000 B
  unsigned short* pbuf = (unsigned short*)(ws + 64000000);      //  67,108,864 B
  unsigned int* pooled = (unsigned int*)(ws + 131108864);       //     131,072 B
  unsigned short* WT_all = (unsigned short*)(ws + 131239936);   //     163,840 B
  float* biasEW = (float*)(ws + 131403776);                     //       2,560 B
  unsigned short* WcT = (unsigned short*)(ws + 131406336);      //     163,840 B
  unsigned short* UfT = (unsigned short*)(ws + 131570176);      //     131,072 B
  unsigned short* UbT = (unsigned short*)(ws + 131701248);      //     131,072 B

  hipMemsetAsync(pooled, 0, B_ * C_ * sizeof(unsigned int), stream);
  prep_kernel<<<64, 256, 0, stream>>>(Wf, Wb, Wc, Uf, Ub, bf_, bb_, WT_all,
                                      biasEW, WcT, UfT, UbT);
  ew_kernel<<<V_ / 16, 256, 0, stream>>>(emb, WT_all, biasEW, EW);
  rnn_kernel<<<32, 512, 0, stream>>>(idxL, idxR, EW, UfT, UbT, WcT, pbuf);
  pool_kernel<<<256, 256, 0, stream>>>(idxC, EW, pbuf, bc, pooled);
  dense_kernel<<<1, 256, 0, stream>>>(pooled, Wd, bd, (float*)d_out);
}

// Round 10
// 689.577 us; speedup vs baseline: 1.0341x; 1.0341x over previous
//
#include <hip/hip_runtime.h>
#include <hip/hip_bf16.h>

// RCNN: bidirectional simple-RNN + conv1x1 + global max pool + dense sigmoid
// B=256 T=512 V=50000 E=128 H=256 C=128
//
// Round-10 structure: bare R4 recurrence + fully-parallel conv.
//  - xwh buffer [512 rows][T][256 shorts]: row (dir*256 + b0 + u) holds
//    "unit" u (cols [16u,16u+16) x 16 batches) at each t. embxw writes xw
//    there; rnn overwrites each slot with h in place (same-block, race-free).
//  - rnn: EXACT R4 config (32 blocks = 16 btiles x 2 dirs, 8 waves x 32
//    cols, 2 waves/SIMD, C-seeded MFMA, T-unroll x2, prefetch-4, LDS-only
//    barrier) - measured 373 us. NOTHING parallel-in-t lives here (R9's
//    fused conv cost +116 us of serial MFMA issue).
//  - ECmid[V][128] = Wc_mid^T emb per VOCAB row (12.8 MB) - e_cur conv
//    partial gathered at pool time, no per-token recompute.
//  - convpool: 512 blocks; stage h tiles through LDS (unit stride 258
//    shorts -> 2 lanes/bank = free), k=512 GEMM vs register Wc frags,
//    + gathered ECmid, max over t, tanh after max, atomicMax.

#define B_ 256
#define T_ 512
#define E_ 128
#define H_ 256
#define C_ 128
#define V_ 50000

typedef __attribute__((ext_vector_type(8))) short short8;
typedef __attribute__((ext_vector_type(4))) float float4v;
typedef __attribute__((ext_vector_type(2))) unsigned int uint2v;

__device__ inline unsigned short f2bf(float f) {
  unsigned u = __float_as_uint(f);
  u += 0x7fffu + ((u >> 16) & 1u);  // RNE
  return (unsigned short)(u >> 16);
}
__device__ inline unsigned pkbf(float a, float b) {
  __hip_bfloat162 h2 = __float22bfloat162_rn(float2{a, b});
  union { __hip_bfloat162 h; unsigned u; } cv;
  cv.h = h2;
  return cv.u;
}
__device__ inline float lo16f(unsigned u) { return __uint_as_float(u << 16); }
__device__ inline float hi16f(unsigned u) { return __uint_as_float(u & 0xffff0000u); }
__device__ inline float fast_tanh(float x) {
  float e = __expf(2.f * x);                 // inf ok -> 1
  float r = __builtin_amdgcn_rcpf(e + 1.f);
  return __builtin_fmaf(-2.f, r, 1.f);
}
__device__ inline unsigned enc_f(float f) {
  unsigned u = __float_as_uint(f);
  return (u & 0x80000000u) ? ~u : (u | 0x80000000u);
}
__device__ inline float dec_f(unsigned key) {
  unsigned bits = (key & 0x80000000u) ? (key ^ 0x80000000u) : ~key;
  return __uint_as_float(bits);
}
__device__ inline void sync_lds() {
  asm volatile("s_waitcnt lgkmcnt(0)\n\ts_barrier" ::: "memory");
}

// ---------------------------------------------------------------------------
// prep: WfT/WbT:[256][128] WcT:[128][640] UfT/UbT:[256][256] (all [n][k]).
// Coalesced reads, strided writes.
// ---------------------------------------------------------------------------
__global__ __launch_bounds__(256) void prep_kernel(
    const float* __restrict__ Wf, const float* __restrict__ Wb,
    const float* __restrict__ Wc, const float* __restrict__ Uf,
    const float* __restrict__ Ub,
    unsigned short* __restrict__ WfT, unsigned short* __restrict__ WbT,
    unsigned short* __restrict__ WcT, unsigned short* __restrict__ UfT,
    unsigned short* __restrict__ UbT) {
  int gid = blockIdx.x * 256 + threadIdx.x;
  int stride = gridDim.x * 256;
  for (int i = gid; i < 128 * 256; i += stride) {  // Wf/Wb [128][256]
    int k = i >> 8, n = i & 255;
    WfT[n * 128 + k] = f2bf(Wf[i]);
    WbT[n * 128 + k] = f2bf(Wb[i]);
  }
  for (int i = gid; i < 640 * 128; i += stride) {  // Wc [640][128]
    int k = i >> 7, n = i & 127;
    WcT[n * 640 + k] = f2bf(Wc[i]);
  }
  for (int i = gid; i < 256 * 256; i += stride) {  // Uf/Ub [256][256]
    int k = i >> 8, n = i & 255;
    UfT[n * 256 + k] = f2bf(Uf[i]);
    UbT[n * 256 + k] = f2bf(Ub[i]);
  }
}

// ---------------------------------------------------------------------------
// embxw: xw^T = W^T e^T + b, packed units into xwh rows.
// grid (128 tquads, 16 btiles, 2 dirs), 256 thr (4 waves x 64 out-cols).
// ---------------------------------------------------------------------------
__global__ __launch_bounds__(256) void embxw_kernel(
    const int* __restrict__ idxL, const int* __restrict__ idxR,
    const float* __restrict__ emb,
    const unsigned short* __restrict__ WfT, const unsigned short* __restrict__ WbT,
    const float* __restrict__ bfv, const float* __restrict__ bbv,
    unsigned short* __restrict__ xwh) {
  const int dir = blockIdx.z;
  const int t0 = blockIdx.x * 4;
  const int b0 = blockIdx.y * 16;
  const int tid = threadIdx.x;
  const int w = tid >> 6, lane = tid & 63, q = lane >> 4, l15 = lane & 15;

  const int* __restrict__ idx = dir ? idxR : idxL;
  const unsigned short* __restrict__ WT = dir ? WbT : WfT;
  const float* __restrict__ bias = dir ? bbv : bfv;

  short8 wfr[4][4];
#pragma unroll
  for (int mt = 0; mt < 4; ++mt)
#pragma unroll
    for (int kt = 0; kt < 4; ++kt)
      wfr[mt][kt] = *(const short8*)(WT + (64 * w + 16 * mt + l15) * 128 +
                                     kt * 32 + q * 8);
  float4v bv[4];
#pragma unroll
  for (int mt = 0; mt < 4; ++mt)
    bv[mt] = *(const float4v*)(bias + 64 * w + 16 * mt + 4 * q);

#pragma unroll 1
  for (int j = 0; j < 4; ++j) {
    const int t = t0 + j;
    const int er = idx[(b0 + l15) * T_ + t];
    const float* ep = emb + (size_t)er * E_;
    short8 efr[4];
#pragma unroll
    for (int kt = 0; kt < 4; ++kt) {
      const float* p8 = ep + kt * 32 + q * 8;
      float4v a0 = *(const float4v*)p8;
      float4v a1 = *(const float4v*)(p8 + 4);
      union { unsigned u[4]; short8 s; } cv;
      cv.u[0] = pkbf(a0[0], a0[1]);
      cv.u[1] = pkbf(a0[2], a0[3]);
      cv.u[2] = pkbf(a1[0], a1[1]);
      cv.u[3] = pkbf(a1[2], a1[3]);
      efr[kt] = cv.s;
    }
    float4v acc[4];
#pragma unroll
    for (int mt = 0; mt < 4; ++mt) acc[mt] = (float4v){0.f, 0.f, 0.f, 0.f};
#pragma unroll
    for (int kt = 0; kt < 4; ++kt)
#pragma unroll
      for (int mt = 0; mt < 4; ++mt)
        acc[mt] = __builtin_amdgcn_mfma_f32_16x16x32_bf16(wfr[mt][kt], efr[kt],
                                                          acc[mt], 0, 0, 0);
#pragma unroll
    for (int mt = 0; mt < 4; ++mt) {
      float4v v = acc[mt] + bv[mt];
      uint2v pk = {pkbf(v[0], v[1]), pkbf(v[2], v[3])};
      *(uint2v*)(xwh +
                 ((size_t)(dir * 256 + b0 + 4 * w + mt) * T_ + t) * 256 +
                 lane * 4) = pk;
    }
  }
}

// ---------------------------------------------------------------------------
// ewmid: ECmid[V][128] = Wc_mid^T emb^T per vocab row. grid 3125 x 256 thr;
// 16 rows/block, 4 waves x 32 c-cols (2 m-tiles).
// ---------------------------------------------------------------------------
__global__ __launch_bounds__(256) void ewmid_kernel(
    const float* __restrict__ emb, const unsigned short* __restrict__ WcT,
    unsigned short* __restrict__ ECmid) {
  const int r0 = blockIdx.x * 16;
  const int tid = threadIdx.x;
  const int w = tid >> 6, lane = tid & 63, q = lane >> 4, l15 = lane & 15;

  short8 wfr[2][4];
#pragma unroll
  for (int mt = 0; mt < 2; ++mt)
#pragma unroll
    for (int kt = 0; kt < 4; ++kt)
      wfr[mt][kt] = *(const short8*)(WcT +
                                     (size_t)(32 * w + 16 * mt + l15) * 640 +
                                     256 + kt * 32 + q * 8);
  short8 efr[4];
#pragma unroll
  for (int kt = 0; kt < 4; ++kt) {
    const float* p8 = emb + (size_t)(r0 + l15) * E_ + kt * 32 + q * 8;
    float4v a0 = *(const float4v*)p8;
    float4v a1 = *(const float4v*)(p8 + 4);
    union { unsigned u[4]; short8 s; } cv;
    cv.u[0] = pkbf(a0[0], a0[1]);
    cv.u[1] = pkbf(a0[2], a0[3]);
    cv.u[2] = pkbf(a1[0], a1[1]);
    cv.u[3] = pkbf(a1[2], a1[3]);
    efr[kt] = cv.s;
  }
  float4v acc[2];
  acc[0] = (float4v){0.f, 0.f, 0.f, 0.f};
  acc[1] = (float4v){0.f, 0.f, 0.f, 0.f};
#pragma unroll
  for (int kt = 0; kt < 4; ++kt)
#pragma unroll
    for (int mt = 0; mt < 2; ++mt)
      acc[mt] = __builtin_amdgcn_mfma_f32_16x16x32_bf16(wfr[mt][kt], efr[kt],
                                                        acc[mt], 0, 0, 0);
#pragma unroll
  for (int mt = 0; mt < 2; ++mt) {
    uint2v pk = {pkbf(acc[mt][0], acc[mt][1]), pkbf(acc[mt][2], acc[mt][3])};
    *(uint2v*)(ECmid + (size_t)(r0 + l15) * 128 + 32 * w + 16 * mt + 4 * q) =
        pk;
  }
}

// ---------------------------------------------------------------------------
// rnn: EXACT R4. h_t = tanh(U^T h ; C-seed = xw_t). One chain per block,
// 8 waves x 32 cols. 32 blocks. Unroll x2, prefetch 4, in-place h store.
// ---------------------------------------------------------------------------
__global__ __launch_bounds__(512, 2) void rnn_kernel(
    unsigned short* xwh, const unsigned short* __restrict__ UfT,
    const unsigned short* __restrict__ UbT) {
  const int dir = blockIdx.x & 1;
  const int b0 = (blockIdx.x >> 1) * 16;
  const unsigned short* __restrict__ UT = dir ? UbT : UfT;
  const int tstep = dir ? -1 : 1;
  const int t0 = dir ? (T_ - 1) : 0;
  const ptrdiff_t dstep = (ptrdiff_t)tstep * 256;  // shorts per t-step

  const int tid = threadIdx.x;
  const int wv = tid >> 6, lane = tid & 63, q = lane >> 4, l15 = lane & 15;

  // stride 280 shorts: b128 bank-start 4*(3*l15+q)%32 -> 2-way (free)
  __shared__ __attribute__((aligned(16))) unsigned short hbuf[2][16][280];
  unsigned short* hb0 = &hbuf[0][0][0];
  unsigned short* hb1 = &hbuf[1][0][0];

  for (int i = tid; i < 16 * 280; i += 512) hb0[i] = 0;

  // U^T A-fragments for this wave's 32 output cols
  short8 ufr[2][8];
#pragma unroll
  for (int mt = 0; mt < 2; ++mt)
#pragma unroll
    for (int kt = 0; kt < 8; ++kt)
      ufr[mt][kt] = *(const short8*)(UT + (32 * wv + 16 * mt + l15) * H_ +
                                     kt * 32 + q * 8);

  // per-lane unit pointers: units u = 2*wv + mt
  unsigned short* ptrS[2];        // store slot (step t of current pair)
  const unsigned short* ptrL[2];  // load slot (t + 4*tstep)
  uint2v curA[2], curB[2], infA[2], infB[2];
#pragma unroll
  for (int mt = 0; mt < 2; ++mt) {
    unsigned short* base =
        xwh + (size_t)(dir * 256 + b0 + 2 * wv + mt) * T_ * 256 + lane * 4;
    unsigned short* bt = base + (ptrdiff_t)t0 * 256;
    curA[mt] = *(const uint2v*)(bt);
    curB[mt] = *(const uint2v*)(bt + dstep);
    infA[mt] = *(const uint2v*)(bt + 2 * dstep);
    infB[mt] = *(const uint2v*)(bt + 3 * dstep);
    ptrS[mt] = bt;
    ptrL[mt] = bt + 4 * dstep;
  }

  const unsigned lrd = l15 * 280;            // LDS read row base (shorts)
  const unsigned lwr = l15 * 280 + 32 * wv;  // LDS write base (+16mt+4q)

  __syncthreads();

#pragma unroll 1
  for (int p = 0; p < 256; ++p) {
    // prefetch pair p+2's xw (steps 2p+4, 2p+5)
    uint2v ldA[2], ldB[2];
    if (p < 254) {
#pragma unroll
      for (int mt = 0; mt < 2; ++mt) {
        ldA[mt] = *(const uint2v*)(ptrL[mt]);
        ldB[mt] = *(const uint2v*)(ptrL[mt] + dstep);
      }
    } else {
#pragma unroll
      for (int mt = 0; mt < 2; ++mt) { ldA[mt] = infA[mt]; ldB[mt] = infB[mt]; }
    }
#pragma unroll
    for (int mt = 0; mt < 2; ++mt) ptrL[mt] += 2 * dstep;

    // ---- STEP A: read hb0, write hb1 ----
    {
      short8 afr[8];
#pragma unroll
      for (int kt = 0; kt < 8; ++kt)
        afr[kt] = *(const short8*)(hb0 + lrd + kt * 32 + q * 8);
      float4v acc[2];
#pragma unroll
      for (int mt = 0; mt < 2; ++mt)
        acc[mt] = (float4v){lo16f(curA[mt].x), hi16f(curA[mt].x),
                            lo16f(curA[mt].y), hi16f(curA[mt].y)};
#pragma unroll
      for (int kt = 0; kt < 8; ++kt)
#pragma unroll
        for (int mt = 0; mt < 2; ++mt)
          acc[mt] = __builtin_amdgcn_mfma_f32_16x16x32_bf16(
              ufr[mt][kt], afr[kt], acc[mt], 0, 0, 0);
#pragma unroll
      for (int mt = 0; mt < 2; ++mt) {
        uint2v hv = {pkbf(fast_tanh(acc[mt][0]), fast_tanh(acc[mt][1])),
                     pkbf(fast_tanh(acc[mt][2]), fast_tanh(acc[mt][3]))};
        *(uint2v*)(hb1 + lwr + 16 * mt + 4 * q) = hv;
        *(uint2v*)ptrS[mt] = hv;
      }
    }
    sync_lds();

    // ---- STEP B: read hb1, write hb0 ----
    {
      short8 afr[8];
#pragma unroll
      for (int kt = 0; kt < 8; ++kt)
        afr[kt] = *(const short8*)(hb1 + lrd + kt * 32 + q * 8);
      float4v acc[2];
#pragma unroll
      for (int mt = 0; mt < 2; ++mt)
        acc[mt] = (float4v){lo16f(curB[mt].x), hi16f(curB[mt].x),
                            lo16f(curB[mt].y), hi16f(curB[mt].y)};
#pragma unroll
      for (int kt = 0; kt < 8; ++kt)
#pragma unroll
        for (int mt = 0; mt < 2; ++mt)
          acc[mt] = __builtin_amdgcn_mfma_f32_16x16x32_bf16(
              ufr[mt][kt], afr[kt], acc[mt], 0, 0, 0);
#pragma unroll
      for (int mt = 0; mt < 2; ++mt) {
        uint2v hv = {pkbf(fast_tanh(acc[mt][0]), fast_tanh(acc[mt][1])),
                     pkbf(fast_tanh(acc[mt][2]), fast_tanh(acc[mt][3]))};
        *(uint2v*)(hb0 + lwr + 16 * mt + 4 * q) = hv;
        *(uint2v*)(ptrS[mt] + dstep) = hv;
      }
    }
#pragma unroll
    for (int mt = 0; mt < 2; ++mt) {
      ptrS[mt] += 2 * dstep;
      curA[mt] = infA[mt];
      curB[mt] = infB[mt];
      infA[mt] = ldA[mt];
      infB[mt] = ldB[mt];
    }
    sync_lds();
  }
}

// ---------------------------------------------------------------------------
// convpool: out = tanh(max_t(h @ Wc_fb + ec) + bc). grid 512 (16 btiles x
// 32 tchunks of 16 t), 256 thr (4 waves x 32 c-cols, 2 m-tiles each).
// h staged per-t through LDS (dbuf, unit stride 258 -> 2-way free banks);
// k-rows 0-255 -> Wc[0:256] (h_f), 256-511 -> Wc[384:640] (h_b).
// ---------------------------------------------------------------------------
__global__ __launch_bounds__(256, 2) void convpool_kernel(
    const int* __restrict__ idxC, const unsigned short* __restrict__ xwh,
    const unsigned short* __restrict__ ECmid,
    const unsigned short* __restrict__ WcT, const float* __restrict__ bc,
    unsigned int* __restrict__ pooled) {
  const int btile = blockIdx.x & 15;
  const int tch = blockIdx.x >> 4;
  const int b0 = btile * 16;
  const int t0 = tch * 16;
  const int tid = threadIdx.x;
  const int w = tid >> 6, lane = tid & 63, q = lane >> 4, l15 = lane & 15;

  __shared__ __attribute__((aligned(16))) unsigned short tile[2][32][258];

  // Wc A-fragments: wave w covers c-cols 32w..32w+31 over k=512
  short8 wfr[2][16];
#pragma unroll
  for (int mt = 0; mt < 2; ++mt)
#pragma unroll
    for (int kt = 0; kt < 16; ++kt) {
      const int krow = kt < 8 ? kt * 32 : 384 + (kt - 8) * 32;
      wfr[mt][kt] = *(const short8*)(WcT +
                                     (size_t)(32 * w + 16 * mt + l15) * 640 +
                                     krow + q * 8);
    }
  float4v bv[2];
#pragma unroll
  for (int mt = 0; mt < 2; ++mt)
    bv[mt] = *(const float4v*)(bc + 32 * w + 16 * mt + 4 * q);

  float4v mx[2];
  mx[0] = (float4v){-1e30f, -1e30f, -1e30f, -1e30f};
  mx[1] = mx[0];

  // staging: thread -> unit tid>>3, 8 threads x 64B sweeps of 128B groups
  const int su = tid >> 3, ssub = tid & 7;
  const int srow = su < 16 ? (b0 + su) : (256 + b0 + su - 16);
  const unsigned short* sbase = xwh + (size_t)srow * T_ * 256 + ssub * 8;

#pragma unroll
  for (int j2 = 0; j2 < 4; ++j2)
    *(short8*)&tile[0][su][ssub * 8 + j2 * 64] =
        *(const short8*)(sbase + (size_t)t0 * 256 + j2 * 64);
  sync_lds();

#pragma unroll 1
  for (int j = 0; j < 16; ++j) {
    const int t = t0 + j;
    const int buf = j & 1;
    if (j < 15) {
#pragma unroll
      for (int j2 = 0; j2 < 4; ++j2)
        *(short8*)&tile[buf ^ 1][su][ssub * 8 + j2 * 64] =
            *(const short8*)(sbase + (size_t)(t + 1) * 256 + j2 * 64);
    }
    // e_cur conv partial gather
    const int erow = idxC[(b0 + l15) * T_ + t];
    uint2v ec[2];
#pragma unroll
    for (int mt = 0; mt < 2; ++mt)
      ec[mt] = *(const uint2v*)(ECmid + (size_t)erow * 128 + 32 * w +
                                16 * mt + 4 * q);
    float4v acc[2];
    acc[0] = (float4v){0.f, 0.f, 0.f, 0.f};
    acc[1] = (float4v){0.f, 0.f, 0.f, 0.f};
#pragma unroll
    for (int kt = 0; kt < 16; ++kt) {
      const int u = 2 * (kt & 7) + (q >> 1) + ((kt >= 8) ? 16 : 0);
      const unsigned short* tb = &tile[buf][u][128 * (q & 1) + 4 * l15];
      uint2v c1 = *(const uint2v*)tb;
      uint2v c2 = *(const uint2v*)(tb + 64);
      union { unsigned uu[4]; short8 s; } cv;
      cv.uu[0] = c1.x; cv.uu[1] = c1.y; cv.uu[2] = c2.x; cv.uu[3] = c2.y;
      acc[0] = __builtin_amdgcn_mfma_f32_16x16x32_bf16(wfr[0][kt], cv.s,
                                                       acc[0], 0, 0, 0);
      acc[1] = __builtin_amdgcn_mfma_f32_16x16x32_bf16(wfr[1][kt], cv.s,
                                                       acc[1], 0, 0, 0);
    }
#pragma unroll
    for (int mt = 0; mt < 2; ++mt) {
      float4v v = acc[mt] + (float4v){lo16f(ec[mt].x), hi16f(ec[mt].x),
                                      lo16f(ec[mt].y), hi16f(ec[mt].y)};
#pragma unroll
      for (int i = 0; i < 4; ++i) mx[mt][i] = fmaxf(mx[mt][i], v[i]);
    }
    sync_lds();
  }
#pragma unroll
  for (int mt = 0; mt < 2; ++mt)
#pragma unroll
    for (int i = 0; i < 4; ++i)
      atomicMax(pooled + (b0 + l15) * C_ + 32 * w + 16 * mt + 4 * q + i,
                enc_f(fast_tanh(mx[mt][i] + bv[mt][i])));
}

// ---------------------------------------------------------------------------
// dense: out = sigmoid(pooled @ Wd + bd)  [256,128]@[128,2]
// ---------------------------------------------------------------------------
__global__ __launch_bounds__(256) void dense_kernel(
    const unsigned int* __restrict__ pooled, const float* __restrict__ Wd,
    const float* __restrict__ bd, float* __restrict__ out) {
  int b = threadIdx.x;
  float s0 = bd[0], s1 = bd[1];
#pragma unroll 4
  for (int c = 0; c < C_; ++c) {
    float f = dec_f(pooled[b * C_ + c]);
    s0 += f * Wd[c * 2 + 0];
    s1 += f * Wd[c * 2 + 1];
  }
  out[b * 2 + 0] = 1.f / (1.f + __expf(-s0));
  out[b * 2 + 1] = 1.f / (1.f + __expf(-s1));
}

// ---------------------------------------------------------------------------
extern "C" void kernel_launch(void* const* d_in, const int* in_sizes, int n_in,
                              void* d_out, int out_size, void* d_ws, size_t ws_size,
                              hipStream_t stream) {
  const int* idxC = (const int*)d_in[0];
  const int* idxL = (const int*)d_in[1];
  const int* idxR = (const int*)d_in[2];
  const float* emb = (const float*)d_in[3];
  const float* Wf = (const float*)d_in[4];
  const float* Uf = (const float*)d_in[5];
  const float* bf_ = (const float*)d_in[6];
  const float* Wb = (const float*)d_in[7];
  const float* Ub = (const float*)d_in[8];
  const float* bb_ = (const float*)d_in[9];
  const float* Wc = (const float*)d_in[10];
  const float* bc = (const float*)d_in[11];
  const float* Wd = (const float*)d_in[12];
  const float* bd = (const float*)d_in[13];

  char* ws = (char*)d_ws;
  unsigned short* xwh = (unsigned short*)ws;                    // 134,217,728 B
  unsigned short* ECmid = (unsigned short*)(ws + 134217728);    //  12,800,000 B
  unsigned int* pooled = (unsigned int*)(ws + 147017728);       //     131,072 B
  unsigned short* WfT = (unsigned short*)(ws + 147148800);      //      65,536 B
  unsigned short* WbT = (unsigned short*)(ws + 147214336);      //      65,536 B
  unsigned short* WcT = (unsigned short*)(ws + 147279872);      //     163,840 B
  unsigned short* UfT = (unsigned short*)(ws + 147443712);      //     131,072 B
  unsigned short* UbT = (unsigned short*)(ws + 147574784);      //     131,072 B

  hipMemsetAsync(pooled, 0, B_ * C_ * sizeof(unsigned int), stream);
  prep_kernel<<<64, 256, 0, stream>>>(Wf, Wb, Wc, Uf, Ub, WfT, WbT, WcT, UfT,
                                      UbT);
  embxw_kernel<<<dim3(128, 16, 2), 256, 0, stream>>>(idxL, idxR, emb, WfT,
                                                     WbT, bf_, bb_, xwh);
  ewmid_kernel<<<V_ / 16, 256, 0, stream>>>(emb, WcT, ECmid);
  rnn_kernel<<<32, 512, 0, stream>>>(xwh, UfT, UbT);
  convpool_kernel<<<512, 256, 0, stream>>>(idxC, xwh, ECmid, WcT, bc, pooled);
  dense_kernel<<<1, 256, 0, stream>>>(pooled, Wd, bd, (float*)d_out);
}